// Round 4
// baseline (30405.817 us; speedup 1.0000x reference)
//
#include <hip/hip_runtime.h>
#include <cstdint>
#include <cstddef>

// ---------------------------------------------------------------------------
// TaggingFNNDecoder round 4: persistent cooperative kernel, streamed weights.
//  * Round-3 post-mortem: failure error == round-0 stub error (2.124e-2) ==
//    |ref| vs zero buffer -> the coop launch was silently REJECTED (VGPR
//    ~480 at (256,1): grid == occupancy max, no margin). Logic was sound.
//  * Fix 1: no persistent weight regs. Weight slices streamed per step from
//    L1/L2 (block-private rows, L2-resident). Live regs ~230 ->
//    __launch_bounds__(256,2) caps 256 VGPR -> coop max 512 >= grid 256.
//  * Fix 2: barrier flag stores preceded by explicit s_waitcnt vmcnt(0)
//    (release-without-cache-ops: all cross-block data bypasses L2, nothing
//    dirty to write back). All cross-block state via uint system-scope
//    RELAXED atomics (sc0 sc1 -> LLC is the coherence point; readers bypass
//    caches so no acquire/invalidate needed anywhere).
//  * Fix 3: if hipLaunchCooperativeKernel fails, fall back to a normal
//    launch of the same kernel (256 blocks <= 512 capacity -> co-resident).
// ---------------------------------------------------------------------------

#define Bz   32
#define Tz   256
#define Dz   1024
#define Hz   512
#define NK   128
#define IN0  (Dz + NK)      // 1152
#define NBLK 256
#define BH   (Bz * Hz)      // 16384

// ---- system-scope relaxed (cache-bypassing) scalar ld/st, uint-typed ----
__device__ __forceinline__ float ldsys(const float* p) {
  return __uint_as_float(__hip_atomic_load((const unsigned int*)p,
         __ATOMIC_RELAXED, __HIP_MEMORY_SCOPE_SYSTEM));
}
__device__ __forceinline__ void stsys(float* p, float v) {
  __hip_atomic_store((unsigned int*)p, __float_as_uint(v),
         __ATOMIC_RELAXED, __HIP_MEMORY_SCOPE_SYSTEM);
}
__device__ __forceinline__ float4 ldsys4(const float* p) {
  float4 v; v.x = ldsys(p); v.y = ldsys(p + 1); v.z = ldsys(p + 2); v.w = ldsys(p + 3);
  return v;
}
__device__ __forceinline__ float2 ldsys2(const float* p) {
  float2 v; v.x = ldsys(p); v.y = ldsys(p + 1); return v;
}
__device__ __forceinline__ void dot4(float& acc, const float4 w, const float4 a) {
  acc = fmaf(w.x, a.x, acc); acc = fmaf(w.y, a.y, acc);
  acc = fmaf(w.z, a.z, acc); acc = fmaf(w.w, a.w, acc);
}
__device__ __forceinline__ float sigf(float x) { return 1.0f / (1.0f + expf(-x)); }

// ---------------- grid barrier: LLC flags, zero cache-maintenance ---------
// slots: bar + b*16 (64B spacing); gen: bar + NBLK*16. g monotonic 1,2,...
__device__ __forceinline__ void gbar(unsigned int* bar, unsigned int g) {
  // drain this thread's outstanding global stores (release w/o cache ops:
  // all cross-block data stores are L2-bypassing, nothing dirty to flush)
  asm volatile("s_waitcnt vmcnt(0)" ::: "memory");
  __syncthreads();
  if (threadIdx.x == 0)
    __hip_atomic_store(bar + blockIdx.x * 16, g,
                       __ATOMIC_RELAXED, __HIP_MEMORY_SCOPE_SYSTEM);
  if (blockIdx.x == NBLK - 1) {
    unsigned int* ws = bar + threadIdx.x * 16;   // one slot per lane
    while (__hip_atomic_load(ws, __ATOMIC_RELAXED, __HIP_MEMORY_SCOPE_SYSTEM) < g)
      __builtin_amdgcn_s_sleep(1);
    __syncthreads();
    if (threadIdx.x == 0) {
      asm volatile("s_waitcnt vmcnt(0)" ::: "memory");
      __hip_atomic_store(bar + NBLK * 16, g,
                         __ATOMIC_RELAXED, __HIP_MEMORY_SCOPE_SYSTEM);
    }
  } else if (threadIdx.x == 0) {
    while (__hip_atomic_load(bar + NBLK * 16, __ATOMIC_RELAXED,
                             __HIP_MEMORY_SCOPE_SYSTEM) < g)
      __builtin_amdgcn_s_sleep(1);
  }
  __syncthreads();
}

// ---------------- 64-lane k-reduction butterfly ---------------------------
// vals[0..63] per lane; after 6 value-halving stages lane l's vals[0] is the
// full 64-lane sum of original index rev6(l). (Verified by induction: after
// stage st, vals[v] = partial sum of index v + (32>>st)*bit_st(lane)+... .)
__device__ __forceinline__ float wave_reduce64(float* vals) {
  const int lane = threadIdx.x & 63;
  #pragma unroll
  for (int st = 0; st < 6; ++st) {
    const int mask = 1 << st;
    const int half = 32 >> st;
    const bool hi = (lane & mask) != 0;
    #pragma unroll
    for (int v = 0; v < 32; ++v) {
      if (v < half) {
        float send = hi ? vals[v] : vals[v + half];
        float recv = __shfl_xor(send, mask, 64);
        float keep = hi ? vals[v + half] : vals[v];
        vals[v] = keep + recv;
      }
    }
  }
  return vals[0];
}

// ---------------- output head + softmax (block bb = batch bb) -------------
template <bool SYS>
__device__ void c_slot(const float* __restrict__ src, int t, int bb,
                       const float* __restrict__ W_out, const float* __restrict__ b_out,
                       const float* __restrict__ mask,
                       float* __restrict__ smg, float* __restrict__ out,
                       float (*cpart)[2], float* wred) {
  const int tid = threadIdx.x;
  const int n = tid & 127, kh = tid >> 7;
  float p = 0.0f;
  const float* w  = W_out + (size_t)n * Hz + kh * 256;
  const float* s2 = src + kh * 256;
  #pragma unroll 8
  for (int k = 0; k < 256; k += 4) {
    float4 sv = SYS ? ldsys4(s2 + k) : *(const float4*)(s2 + k);
    float4 wv = *(const float4*)(w + k);
    p += sv.x * wv.x + sv.y * wv.y + sv.z * wv.z + sv.w * wv.w;
  }
  cpart[n][kh] = p;
  __syncthreads();
  float logit = 0.0f;
  if (tid < 128) logit = cpart[n][0] + cpart[n][1] + b_out[n];
  float m = logit;
  #pragma unroll
  for (int off = 32; off >= 1; off >>= 1) m = fmaxf(m, __shfl_xor(m, off));
  if ((tid & 63) == 0 && tid < 128) wred[tid >> 6] = m;
  __syncthreads();
  float M = fmaxf(wred[0], wred[1]);
  float e = (tid < 128) ? expf(logit - M) : 0.0f;
  float sfx = e;
  #pragma unroll
  for (int off = 32; off >= 1; off >>= 1) sfx += __shfl_xor(sfx, off);
  if ((tid & 63) == 0 && tid < 128) wred[2 + (tid >> 6)] = sfx;
  __syncthreads();
  float S = wred[2] + wred[3];
  if (tid < 128) stsys(smg + bb * NK + n, e / S);

  if (t >= 0) {
    float mk = mask[bb * Tz + t];
    float lm = (tid < 128) ? (logit + (1.0f - mk) * (-1e32f)) : 0.0f;
    float m2 = lm;
    #pragma unroll
    for (int off = 32; off >= 1; off >>= 1) m2 = fmaxf(m2, __shfl_xor(m2, off));
    if ((tid & 63) == 0 && tid < 128) wred[4 + (tid >> 6)] = m2;
    __syncthreads();
    float M2 = fmaxf(wred[4], wred[5]);
    float e2 = (tid < 128) ? expf(lm - M2) : 0.0f;
    float s2r = e2;
    #pragma unroll
    for (int off = 32; off >= 1; off >>= 1) s2r += __shfl_xor(s2r, off);
    if ((tid & 63) == 0 && tid < 128) wred[6 + (tid >> 6)] = s2r;
    __syncthreads();
    float S2 = wred[6] + wred[7];
    if (tid < 128) out[((size_t)bb * Tz + t) * NK + n] = e2 / S2;
  }
}

__device__ __forceinline__ int rowg(int r, int j0) {
  return (r >> 1) * Hz + j0 + (r & 1);      // r = gate*2 + jj
}

// ---------------- the persistent kernel -----------------------------------
__global__ void __launch_bounds__(256, 2)
seq_kernel(const float* __restrict__ hiddens,
           const float* __restrict__ h_t, const float* __restrict__ c_t,
           const float* __restrict__ mask,
           const float* __restrict__ W_out, const float* __restrict__ b_out,
           const float* __restrict__ W_ih0, const float* __restrict__ W_hh0,
           const float* __restrict__ b_ih0, const float* __restrict__ b_hh0,
           const float* __restrict__ W_ih1, const float* __restrict__ W_hh1,
           const float* __restrict__ b_ih1, const float* __restrict__ b_hh1,
           float* __restrict__ out,
           float* __restrict__ h1g, float* __restrict__ h2g,
           float* __restrict__ smg, unsigned int* bar) {
  __shared__ float gbuf[8][32];
  __shared__ float cpart[128][2];
  __shared__ float wred[8];
  __shared__ float biasA[8], biasB[8];

  const int tid  = threadIdx.x;
  const int bid  = blockIdx.x;
  const int kg   = tid & 63;        // lane = k-group
  const int bgrp = tid >> 6;        // wave = batch-group (8 batches)
  const int b0   = bgrp * 8;
  const int j0   = 2 * bid;         // block owns hidden units j0, j0+1

  if (tid < 8) {
    const int row = rowg(tid, j0);
    biasA[tid] = b_ih0[row] + b_hh0[row];
    biasB[tid] = b_ih1[row] + b_hh1[row];
  }

  // ---- cell state in registers for all 256 steps ----
  const int cb = tid & 31, cj = (tid >> 5) & 1, jc = j0 + cj;
  float c1r = 0.0f, c2r = 0.0f;
  if (tid < 64) {
    c1r = c_t[cb * Hz + jc];
    c2r = c_t[BH + cb * Hz + jc];
    stsys(h1g + BH + cb * Hz + jc, h_t[cb * Hz + jc]);      // parity-1 init
    stsys(h2g + BH + cb * Hz + jc, h_t[BH + cb * Hz + jc]);
  }
  __syncthreads();
  if (bid < 32)     // sm(-1) from hiddens[:,0,:H]
    c_slot<false>(hiddens + (size_t)bid * Tz * Dz, -1, bid,
                  W_out, b_out, mask, smg, out, cpart, wred);
  unsigned int g = 1;
  gbar(bar, g); ++g;

  for (int t = 0; t < Tz; ++t) {
    const float* h1prev = h1g + ((t + 1) & 1) * BH;
    float*       h1cur  = h1g + (t & 1) * BH;
    const float* h2prev = h2g + ((t + 1) & 1) * BH;
    float*       h2cur  = h2g + (t & 1) * BH;

    // ======== slot A: layer-0 gates over [h1prev | x_t | sm] ========
    {
      float acc[64];
      #pragma unroll
      for (int v = 0; v < 64; ++v) acc[v] = 0.0f;

      // LLC state loads issued first (latency hidden behind x-part work)
      float4 aH0[8], aH1[8]; float2 aS[8];
      #pragma unroll
      for (int b8 = 0; b8 < 8; ++b8)
        aH0[b8] = ldsys4(h1prev + (size_t)(b0 + b8) * Hz + 4 * kg);
      #pragma unroll
      for (int b8 = 0; b8 < 8; ++b8)
        aH1[b8] = ldsys4(h1prev + (size_t)(b0 + b8) * Hz + 256 + 4 * kg);
      #pragma unroll
      for (int b8 = 0; b8 < 8; ++b8)
        aS[b8] = ldsys2(smg + (size_t)(b0 + b8) * NK + 2 * kg);

      // x part: acts + weights from normal caches (read-only inputs)
      const float* xb = hiddens + (size_t)t * Dz + 4 * kg;
      #pragma unroll
      for (int s = 0; s < 4; ++s) {
        float4 ax[8], wx[8];
        #pragma unroll
        for (int b8 = 0; b8 < 8; ++b8)
          ax[b8] = *(const float4*)(xb + (size_t)(b0 + b8) * Tz * Dz + 256 * s);
        #pragma unroll
        for (int r = 0; r < 8; ++r)
          wx[r] = *(const float4*)(W_ih0 + (size_t)rowg(r, j0) * IN0 + 256 * s + 4 * kg);
        #pragma unroll
        for (int r = 0; r < 8; ++r)
          #pragma unroll
          for (int b8 = 0; b8 < 8; ++b8)
            dot4(acc[r * 8 + b8], wx[r], ax[b8]);
      }
      // recurrent part: weight slices streamed (L1/L2-hot, block-private)
      #pragma unroll
      for (int r = 0; r < 8; ++r) {
        const int row = rowg(r, j0);
        float4 w0 = *(const float4*)(W_hh0 + (size_t)row * Hz + 4 * kg);
        float4 w1 = *(const float4*)(W_hh0 + (size_t)row * Hz + 256 + 4 * kg);
        float2 ws = *(const float2*)(W_ih0 + (size_t)row * IN0 + 1024 + 2 * kg);
        #pragma unroll
        for (int b8 = 0; b8 < 8; ++b8) {
          dot4(acc[r * 8 + b8], w0, aH0[b8]);
          dot4(acc[r * 8 + b8], w1, aH1[b8]);
          acc[r * 8 + b8] = fmaf(ws.x, aS[b8].x, acc[r * 8 + b8]);
          acc[r * 8 + b8] = fmaf(ws.y, aS[b8].y, acc[r * 8 + b8]);
        }
      }

      float val = wave_reduce64(acc);
      const int o = (int)(__brev((unsigned)kg) >> 26);   // rev6(lane)
      gbuf[o >> 3][b0 + (o & 7)] = val + biasA[o >> 3];
      __syncthreads();
      if (tid < 64) {
        float gi = gbuf[0 + cj][cb], gf = gbuf[2 + cj][cb];
        float gg = gbuf[4 + cj][cb], go = gbuf[6 + cj][cb];
        c1r = sigf(gf) * c1r + sigf(gi) * tanhf(gg);
        stsys(h1cur + cb * Hz + jc, sigf(go) * tanhf(c1r));
      }
    }
    gbar(bar, g); ++g;

    // ======== slot B: layer-1 gates over [h1cur | h2prev] ========
    {
      float acc[64];
      #pragma unroll
      for (int v = 0; v < 64; ++v) acc[v] = 0.0f;
      float4 a1[8], a2[8], a3[8], a4[8];
      #pragma unroll
      for (int b8 = 0; b8 < 8; ++b8)
        a1[b8] = ldsys4(h1cur + (size_t)(b0 + b8) * Hz + 4 * kg);
      #pragma unroll
      for (int b8 = 0; b8 < 8; ++b8)
        a2[b8] = ldsys4(h1cur + (size_t)(b0 + b8) * Hz + 256 + 4 * kg);
      #pragma unroll
      for (int b8 = 0; b8 < 8; ++b8)
        a3[b8] = ldsys4(h2prev + (size_t)(b0 + b8) * Hz + 4 * kg);
      #pragma unroll
      for (int b8 = 0; b8 < 8; ++b8)
        a4[b8] = ldsys4(h2prev + (size_t)(b0 + b8) * Hz + 256 + 4 * kg);
      #pragma unroll
      for (int r = 0; r < 8; ++r) {
        const int row = rowg(r, j0);
        float4 wi0 = *(const float4*)(W_ih1 + (size_t)row * Hz + 4 * kg);
        float4 wi1 = *(const float4*)(W_ih1 + (size_t)row * Hz + 256 + 4 * kg);
        float4 wh0 = *(const float4*)(W_hh1 + (size_t)row * Hz + 4 * kg);
        float4 wh1v = *(const float4*)(W_hh1 + (size_t)row * Hz + 256 + 4 * kg);
        #pragma unroll
        for (int b8 = 0; b8 < 8; ++b8) {
          dot4(acc[r * 8 + b8], wi0, a1[b8]);
          dot4(acc[r * 8 + b8], wi1, a2[b8]);
          dot4(acc[r * 8 + b8], wh0, a3[b8]);
          dot4(acc[r * 8 + b8], wh1v, a4[b8]);
        }
      }
      float val = wave_reduce64(acc);
      const int o = (int)(__brev((unsigned)kg) >> 26);
      gbuf[o >> 3][b0 + (o & 7)] = val + biasB[o >> 3];
      __syncthreads();
      if (tid < 64) {
        float gi = gbuf[0 + cj][cb], gf = gbuf[2 + cj][cb];
        float gg = gbuf[4 + cj][cb], go = gbuf[6 + cj][cb];
        c2r = sigf(gf) * c2r + sigf(gi) * tanhf(gg);
        stsys(h2cur + cb * Hz + jc, sigf(go) * tanhf(c2r));
      }
    }
    gbar(bar, g); ++g;

    // ======== slot C: logits + softmax + output (blocks 0..31) ========
    if (bid < 32)
      c_slot<true>(h2cur + (size_t)bid * Hz, t, bid,
                   W_out, b_out, mask, smg, out, cpart, wred);
    gbar(bar, g); ++g;
  }
}

// ---------------------------------------------------------------------------
extern "C" void kernel_launch(void* const* d_in, const int* in_sizes, int n_in,
                              void* d_out, int out_size, void* d_ws, size_t ws_size,
                              hipStream_t stream) {
  (void)in_sizes; (void)n_in; (void)out_size; (void)ws_size;
  const float* hiddens = (const float*)d_in[0];
  const float* h_t     = (const float*)d_in[1];
  const float* c_t     = (const float*)d_in[2];
  const float* mask    = (const float*)d_in[3];
  const float* W_out   = (const float*)d_in[4];
  const float* b_out   = (const float*)d_in[5];
  const float* W_ih0   = (const float*)d_in[6];
  const float* W_hh0   = (const float*)d_in[7];
  const float* b_ih0   = (const float*)d_in[8];
  const float* b_hh0   = (const float*)d_in[9];
  const float* W_ih1   = (const float*)d_in[10];
  const float* W_hh1   = (const float*)d_in[11];
  const float* b_ih1   = (const float*)d_in[12];
  const float* b_hh1   = (const float*)d_in[13];
  float* out = (float*)d_out;

  unsigned int* bar = (unsigned int*)d_ws;               // (256*16+16)*4 B
  float* base = (float*)((char*)d_ws + 32768);
  float* h1g  = base;                                    // 2*BH (parity)
  float* h2g  = h1g + 2 * BH;                            // 2*BH
  float* smg  = h2g + 2 * BH;                            // Bz*NK

  hipMemsetAsync(bar, 0, 32768, stream);

  void* ka[] = { (void*)&hiddens, (void*)&h_t, (void*)&c_t, (void*)&mask,
                 (void*)&W_out, (void*)&b_out, (void*)&W_ih0, (void*)&W_hh0,
                 (void*)&b_ih0, (void*)&b_hh0, (void*)&W_ih1, (void*)&W_hh1,
                 (void*)&b_ih1, (void*)&b_hh1, (void*)&out,
                 (void*)&h1g, (void*)&h2g, (void*)&smg, (void*)&bar };
  hipError_t err = hipLaunchCooperativeKernel((void*)seq_kernel, dim3(NBLK),
                                              dim3(256), ka, 0, stream);
  if (err != hipSuccess) {
    // fallback: normal launch. 256 blocks at <=256 VGPR (2 blocks/CU capacity)
    // are co-resident by capacity, so the grid barrier remains valid.
    hipLaunchKernelGGL(seq_kernel, dim3(NBLK), dim3(256), 0, stream,
                       hiddens, h_t, c_t, mask, W_out, b_out, W_ih0, W_hh0,
                       b_ih0, b_hh0, W_ih1, W_hh1, b_ih1, b_hh1, out,
                       h1g, h2g, smg, bar);
  }
}